// Round 1
// baseline (30.759 us; speedup 1.0000x reference)
//
#include <hip/hip_runtime.h>
#include <hip/hip_bf16.h>
#include <math.h>

// Problem constants (from reference)
#define BB 256
#define NN 16
#define MM 128
#define VV 512
#define KK 8
#define NP1 17   // N+1

// ---------------------------------------------------------------------------
// Phase A: one 64-lane wave per (b,k).
//  1) gumbel-argmax over the 17 (masked) logits -> idx in [0,17)
//     (idx==0 means PAD slice -> contributes nothing)
//  2) olen = 1 + last row m of decodings[b,idx-1] where max(row[1:]) > row[0]
//     scanned backward (expected ~1 row read for random data)
// ---------------------------------------------------------------------------
__global__ __launch_bounds__(256) void phaseA(
        const float* __restrict__ decodings,   // [B,N,M,V]
        const float* __restrict__ dec_logits,  // [B,K,N+1]
        const float* __restrict__ noise,       // [B,K,N+1]
        const int*   __restrict__ ttypes,      // [B]
        const int*   __restrict__ spans,       // [B]
        int* __restrict__ ws_idx,              // [B*K]
        int* __restrict__ ws_olen)             // [B*K]
{
    const int wave = (blockIdx.x * blockDim.x + threadIdx.x) >> 6;
    const int lane = threadIdx.x & 63;
    const int b = wave >> 3;      // K = 8
    const int k = wave & 7;

    int idx;
    if (ttypes[b] == 20) {
        idx = (k == 0) ? 1 : 0;   // start_template: row0 -> one-hot(1), rest -> one-hot(0)
    } else {
        const int span = spans[b];
        float score = -INFINITY;
        int   bi    = 1000;
        if (lane < NP1) {
            const int base = (b * KK + k) * NP1 + lane;
            float logit = dec_logits[base];
            float u     = noise[base];
            float g     = -logf(-logf(u));            // gumbel noise
            float m     = (lane <= span) ? logit : -1e9f;
            score = m + g;
            bi    = lane;
        }
        // wave argmax, first-index tie-break (matches jnp.argmax)
        for (int off = 32; off; off >>= 1) {
            float s2 = __shfl_down(score, off);
            int   b2 = __shfl_down(bi, off);
            if (s2 > score || (s2 == score && b2 < bi)) { score = s2; bi = b2; }
        }
        idx = __shfl(bi, 0);
    }

    int olen = 0;
    if (idx > 0) {
        const float* base = decodings + (((size_t)b * NN + (idx - 1)) * MM) * (size_t)VV;
        for (int m = MM - 1; m >= 0; --m) {
            const float4* row = (const float4*)(base + (size_t)m * VV);
            float4 a = row[lane];        // v = 4*lane   .. 4*lane+3
            float4 c = row[64 + lane];   // v = 256+4*la .. +3
            float r0 = __shfl(a.x, 0);   // row[0]
            float mx = fmaxf(fmaxf(a.y, a.z), a.w);
            if (lane != 0) mx = fmaxf(mx, a.x);      // exclude v=0 only on lane 0
            mx = fmaxf(mx, fmaxf(fmaxf(c.x, c.y), fmaxf(c.z, c.w)));
            for (int off = 32; off; off >>= 1) mx = fmaxf(mx, __shfl_xor(mx, off));
            if (mx > r0) { olen = m + 1; break; }    // argmax(row) != 0
        }
    }

    if (lane == 0) {
        ws_idx[wave]  = idx;
        ws_olen[wave] = olen;
    }
}

// ---------------------------------------------------------------------------
// Phase B: placement gather. 4 blocks per batch, each handles 32 output rows.
// Builds row -> source-row map in shared (K=8 segment prefix with clipping),
// then float4 gather / zero fill.
// ---------------------------------------------------------------------------
__global__ __launch_bounds__(256) void phaseB(
        const float* __restrict__ decodings,   // [B,N,M,V]
        const int*   __restrict__ ws_idx,
        const int*   __restrict__ ws_olen,
        float* __restrict__ out)               // [B,M,V]
{
    const int b    = blockIdx.x >> 2;
    const int part = blockIdx.x & 3;
    const int tid  = threadIdx.x;

    __shared__ int s_src[32];   // source row (n*M + src_m) or -1, for our 32 rows
    if (tid < 32) {
        const int m_out = part * 32 + tid;
        int start = 0;
        int src   = -1;
        #pragma unroll
        for (int k = 0; k < KK; ++k) {
            int idx = ws_idx[b * KK + k];
            int ol  = ws_olen[b * KK + k];
            ol = min(ol, MM - start);               // clip to remaining space
            if (m_out >= start && m_out < start + ol)
                src = (idx - 1) * MM + (m_out - start);
            start += ol;
        }
        s_src[tid] = src;
    }
    __syncthreads();

    const float4* dec4 = (const float4*)(decodings + (size_t)b * NN * MM * VV);
    float4*       out4 = (float4*)(out + ((size_t)b * MM + part * 32) * (size_t)VV);

    #pragma unroll
    for (int i = 0; i < 16; ++i) {
        int flat    = i * 256 + tid;   // float4 index within our 32 rows (4096 total)
        int m_local = flat >> 7;       // 128 float4 per row
        int v4      = flat & 127;
        int s       = s_src[m_local];
        float4 val;
        if (s >= 0) val = dec4[(size_t)s * 128 + v4];
        else        val = make_float4(0.f, 0.f, 0.f, 0.f);
        out4[flat] = val;
    }
}

extern "C" void kernel_launch(void* const* d_in, const int* in_sizes, int n_in,
                              void* d_out, int out_size, void* d_ws, size_t ws_size,
                              hipStream_t stream) {
    const float* decodings  = (const float*)d_in[0];
    const float* dec_logits = (const float*)d_in[1];
    const float* noise      = (const float*)d_in[2];
    const int*   ttypes     = (const int*)d_in[3];
    const int*   spans      = (const int*)d_in[4];
    float* out = (float*)d_out;

    int* ws_idx  = (int*)d_ws;
    int* ws_olen = ws_idx + BB * KK;

    // Phase A: B*K = 2048 waves, 4 waves per block -> 512 blocks
    phaseA<<<(BB * KK) / 4, 256, 0, stream>>>(decodings, dec_logits, noise,
                                              ttypes, spans, ws_idx, ws_olen);
    // Phase B: 4 blocks per batch -> 1024 blocks
    phaseB<<<BB * 4, 256, 0, stream>>>(decodings, ws_idx, ws_olen, out);
}

// Round 2
// 27.900 us; speedup vs baseline: 1.1025x; 1.1025x over previous
//
#include <hip/hip_runtime.h>
#include <hip/hip_bf16.h>
#include <math.h>

// Problem constants (from reference)
#define BB 256
#define NN 16
#define MM 128
#define VV 512
#define KK 8
#define NP1 17   // N+1

// ---------------------------------------------------------------------------
// Fused kernel: 2 blocks per batch, 512 threads (8 waves) each.
//
// Step 1 (per block, redundant across the 2 blocks of a batch):
//   wave w computes, for k = w:
//     idx  = gumbel-argmax over the 17 masked logits (0 => PAD slice)
//     olen = 1 + last row m of decodings[b,idx-1] whose argmax != 0,
//            scanned backward (expected ~1 row read for random data)
// Step 2: threads 0..63 build the output-row -> source-row map (K-segment
//   prefix with clipping at M) for this block's 64 rows, in shared.
// Step 3: float4 gather / zero-fill of 64 rows x 512 floats.
// ---------------------------------------------------------------------------
__global__ __launch_bounds__(512) void fused_place(
        const float* __restrict__ decodings,   // [B,N,M,V]
        const float* __restrict__ dec_logits,  // [B,K,N+1]
        const float* __restrict__ noise,       // [B,K,N+1]
        const int*   __restrict__ ttypes,      // [B]
        const int*   __restrict__ spans,       // [B]
        float* __restrict__ out)               // [B,M,V]
{
    const int b    = blockIdx.x >> 1;
    const int part = blockIdx.x & 1;          // which 64-row half of out[b]
    const int tid  = threadIdx.x;
    const int wave = tid >> 6;                // 0..7 == k
    const int lane = tid & 63;
    const int k    = wave;

    __shared__ int s_idx[KK];
    __shared__ int s_olen[KK];
    __shared__ int s_src[64];

    // ---- Step 1: idx + olen for k = wave ----
    int idx;
    if (ttypes[b] == 20) {
        idx = (k == 0) ? 1 : 0;   // start_template: row0 -> one-hot(1), rest -> one-hot(0)
    } else {
        const int span = spans[b];
        float score = -INFINITY;
        int   bi    = 1000;
        if (lane < NP1) {
            const int base = (b * KK + k) * NP1 + lane;
            float logit = dec_logits[base];
            float u     = noise[base];
            float g     = -logf(-logf(u));            // gumbel noise
            float m     = (lane <= span) ? logit : -1e9f;
            score = m + g;
            bi    = lane;
        }
        // wave argmax, first-index tie-break (matches jnp.argmax)
        for (int off = 32; off; off >>= 1) {
            float s2 = __shfl_down(score, off);
            int   b2 = __shfl_down(bi, off);
            if (s2 > score || (s2 == score && b2 < bi)) { score = s2; bi = b2; }
        }
        idx = __shfl(bi, 0);
    }

    int olen = 0;
    if (idx > 0) {
        const float* base = decodings + (((size_t)b * NN + (idx - 1)) * MM) * (size_t)VV;
        for (int m = MM - 1; m >= 0; --m) {
            const float4* row = (const float4*)(base + (size_t)m * VV);
            float4 a = row[lane];        // v = 4*lane .. 4*lane+3
            float4 c = row[64 + lane];   // v = 256+4*lane .. +3
            float r0 = __shfl(a.x, 0);   // row[0]
            float mx = fmaxf(fmaxf(a.y, a.z), a.w);
            if (lane != 0) mx = fmaxf(mx, a.x);      // exclude v=0 only on lane 0
            mx = fmaxf(mx, fmaxf(fmaxf(c.x, c.y), fmaxf(c.z, c.w)));
            for (int off = 32; off; off >>= 1) mx = fmaxf(mx, __shfl_xor(mx, off));
            if (mx > r0) { olen = m + 1; break; }    // argmax(row) != 0
        }
    }

    if (lane == 0) {
        s_idx[k]  = idx;
        s_olen[k] = olen;
    }
    __syncthreads();

    // ---- Step 2: build row -> source map for our 64 rows ----
    if (tid < 64) {
        const int m_out = part * 64 + tid;
        int start = 0;
        int src   = -1;
        #pragma unroll
        for (int kk = 0; kk < KK; ++kk) {
            int id = s_idx[kk];
            int ol = min(s_olen[kk], MM - start);    // clip to remaining space
            if (m_out >= start && m_out < start + ol)
                src = (id - 1) * MM + (m_out - start);
            start += ol;
        }
        s_src[tid] = src;
    }
    __syncthreads();

    // ---- Step 3: gather 64 rows x 512 floats (8192 float4, 512 threads) ----
    const float4* dec4 = (const float4*)(decodings + (size_t)b * NN * MM * VV);
    float4*       out4 = (float4*)(out + ((size_t)b * MM + part * 64) * (size_t)VV);

    #pragma unroll
    for (int i = 0; i < 16; ++i) {
        int flat    = i * 512 + tid;   // float4 index within our 64 rows
        int m_local = flat >> 7;       // 128 float4 per row
        int v4      = flat & 127;
        int s       = s_src[m_local];
        float4 val;
        if (s >= 0) val = dec4[(size_t)s * 128 + v4];
        else        val = make_float4(0.f, 0.f, 0.f, 0.f);
        out4[flat] = val;
    }
}

extern "C" void kernel_launch(void* const* d_in, const int* in_sizes, int n_in,
                              void* d_out, int out_size, void* d_ws, size_t ws_size,
                              hipStream_t stream) {
    const float* decodings  = (const float*)d_in[0];
    const float* dec_logits = (const float*)d_in[1];
    const float* noise      = (const float*)d_in[2];
    const int*   ttypes     = (const int*)d_in[3];
    const int*   spans      = (const int*)d_in[4];
    float* out = (float*)d_out;

    // 2 blocks per batch -> 512 blocks of 512 threads
    fused_place<<<BB * 2, 512, 0, stream>>>(decodings, dec_logits, noise,
                                            ttypes, spans, out);
}